// Round 7
// baseline (548.500 us; speedup 1.0000x reference)
//
#include <hip/hip_runtime.h>
#include <math.h>

// LocalRelationBlock fused kernel for MI355X (gfx950).
// B=8192, C=256, H=W=5, G=8 groups, SE_HID=64.
// R7: occupancy-first. 26-row [pixel][channel] layout for x AND y1n (row 25 =
//     permanent zero row); conv2 taps = per-lane row shifts (roA[9], compile-
//     time indexed, fully unrolled 144-step loop); CPB=528 -> +1 granule/row
//     => <=2-way LDS conflicts; OUTF staged in bf16; no K-split/exchange.
//     LDS 36.5KB + ~80 VGPR -> 3 WG/CU (24 waves). B-prologue race fixed.

typedef short v8s  __attribute__((ext_vector_type(8)));   // 8 x bf16
typedef short v4s  __attribute__((ext_vector_type(4)));   // 4 x bf16
typedef float v16f __attribute__((ext_vector_type(16)));
typedef float v4f  __attribute__((ext_vector_type(4)));

#define NTHREADS 512
#define NB 2
#define CPB 528              // row stride bytes (33 x 16B granules -> +1/row rotation)
#define YROWS 26             // pixel rows 0..24 + zero row 25
#define YSB (YROWS*CPB)      // 13728 bytes per sample

#define Y_BYTES  (NB*YSB)                 // 27456 (OUTF bf16 overlay: 25600 fits)
#define GB_OFF   (Y_BYTES)                // g1,b1,g2,b2 : 1024 f32
#define MASK_OFF (GB_OFF + 4096)          // [NB][32] f32
#define POOL_OFF (MASK_OFF + 256)         // [NB][256] f32
#define H_OFF    (POOL_OFF + 2048)        // [NB][64] f32
#define GATE_OFF (H_OFF + 512)            // [NB][256] f32
#define INVD_OFF (GATE_OFF + 2048)        // [NB] f32
#define SMEM_BYTES (INVD_OFF + 64)        // 36480

__device__ __forceinline__ unsigned short f2bf(float f){
  unsigned u = __float_as_uint(f);
  u = u + 0x7fffu + ((u >> 16) & 1u);          // RTNE
  return (unsigned short)(u >> 16);
}
__device__ __forceinline__ float bf2f(unsigned short u){
  return __uint_as_float(((unsigned)u) << 16);
}
// erf via Abramowitz-Stegun 7.1.26 (|eps| < 1.5e-7)
__device__ __forceinline__ float gelu_f(float v){
  float z  = fabsf(v) * 0.70710678118654752f;
  float t  = __builtin_amdgcn_rcpf(fmaf(0.3275911f, z, 1.0f));
  float e  = __builtin_amdgcn_exp2f(-z*z*1.4426950408889634f);
  float p  = fmaf(1.061405429f, t, -1.453152027f);
  p = fmaf(p, t, 1.421413741f);
  p = fmaf(p, t, -0.284496736f);
  p = fmaf(p, t, 0.254829592f);
  float er = fmaf(-p*t, e, 1.0f);
  er = __builtin_copysignf(er, v);
  return 0.5f*v*(1.0f + er);
}

// W1 -> [s=0..15][o=256][16] (k = s*16+kk).
// W2 -> [s=tap*16+u][o=256][16] (k-within-tap = u*16+kk).
__global__ void prep_kernel(const float* __restrict__ W1, const float* __restrict__ W2,
                            const float* __restrict__ fc1w, const float* __restrict__ fc2w,
                            unsigned short* __restrict__ w1p, unsigned short* __restrict__ w2p,
                            float* __restrict__ fc1t, float* __restrict__ fc2t)
{
  int t = blockIdx.x*blockDim.x + threadIdx.x;
  int stride = gridDim.x*blockDim.x;
  for (int i=t; i<16*256*16; i+=stride){
    int s=i>>12, o=(i>>4)&255, kk=i&15;
    w1p[i] = f2bf(W1[o*256 + s*16 + kk]);
  }
  for (int i=t; i<144*256*16; i+=stride){
    int s=i>>12, o=(i>>4)&255, kk=i&15;
    int tap=s>>4, u=s&15;
    w2p[i] = f2bf(W2[o*2304 + (u*16+kk)*9 + tap]);
  }
  for (int i=t; i<256*64; i+=stride){ int c=i>>6, h=i&63; fc1t[i]=fc1w[h*256+c]; }
  for (int i=t; i<64*256; i+=stride){ int k=i>>8, c=i&255; fc2t[i]=fc2w[c*64+k]; }
}

__global__ __launch_bounds__(NTHREADS, 6) void lrb_main(
    const float* __restrict__ xg, const float* __restrict__ maskg,
    const float* __restrict__ g1, const float* __restrict__ b1,
    const float* __restrict__ g2, const float* __restrict__ b2,
    const unsigned short* __restrict__ w1p, const unsigned short* __restrict__ w2p,
    const float* __restrict__ fc1t, const float* __restrict__ fc1b,
    const float* __restrict__ fc2t, const float* __restrict__ fc2b,
    float* __restrict__ outg, float* __restrict__ gateg)
{
  extern __shared__ char smem[];
  unsigned short* OUTFu = (unsigned short*)smem;   // [NB][256][25] bf16, reuses Y
  float* GB   = (float*)(smem + GB_OFF);
  float* MS   = (float*)(smem + MASK_OFF);
  float* POOL = (float*)(smem + POOL_OFF);
  float* HS   = (float*)(smem + H_OFF);
  float* GT   = (float*)(smem + GATE_OFF);
  float* INVD = (float*)(smem + INVD_OFF);

  const int tid  = threadIdx.x;
  const int lane = tid & 63;
  const int wid  = tid >> 6;     // 0..7 : M-group = GN group (32 ch)
  const int p    = lane & 31;    // pixel slot (MFMA col / A row)
  const int half = lane >> 5;    // k-half within 16
  const int hx   = half << 4;    // byte offset of k-half
  const bool pv  = (p < 25);
  const int b0   = blockIdx.x * NB;

  // ---------------- phase 1: zero row 25 (both samples) + params + mask ----
  {
    int4 z4; z4.x=z4.y=z4.z=z4.w=0;
    if (tid < 2*33){
      int nt = tid/33, cc = tid - nt*33;
      *(int4*)(smem + nt*YSB + 25*CPB + cc*16) = z4;
    }
    if (tid >= 64 && tid < 320){
      int c = tid - 64;
      GB[c]=g1[c]; GB[256+c]=b1[c]; GB[512+c]=g2[c]; GB[768+c]=b2[c];
    }
    if (tid >= 320 && tid < 320 + NB*32){
      int t2 = tid - 320;
      int nbb = t2>>5, pp = t2&31;
      MS[t2] = (pp < 25) ? maskg[(size_t)(b0+nbb)*25 + pp] : 0.f;
    }
  }

  // ---------------- geometry ----------------
  const int pr = p/5, ps = p - 5*(p/5);          // pixel (row, col) in 5x5
  const int aoff = (wid*32 + p)*32 + hx;          // A byte offset within a panel
  const char* w1a = (const char*)w1p + aoff;
  const char* w2a = (const char*)w2p + aoff;
  const int prow1 = pv ? p : 25;                  // conv1 B row
  const char* b1base[2] = { smem + prow1*CPB + hx, smem + YSB + prow1*CPB + hx };

  // conv2 per-tap row byte offsets (compile-time indexed under full unroll)
  int roA[9];
  #pragma unroll
  for (int t=0; t<9; ++t){
    int dr = t/3, ds = t - 3*(t/3);
    bool v = pv && (pr+dr >= 1) && (pr+dr <= 5) && (ps+ds >= 1) && (ps+ds <= 5);
    int row = v ? (p + (dr-1)*5 + (ds-1)) : 25;
    roA[t] = row*CPB + hx;
  }

  // conv1 A prologue (global; independent of LDS)
  v8s A1[2], B1[2][2];
  A1[0] = *(const v8s*)(w1a);
  A1[1] = *(const v8s*)(w1a + 8192);

  // ---------------- phase 2: stage x -> rows 0..24 as bf16 [p][c] ----------
  for (int i = tid; i < NB*25*32; i += NTHREADS){
    int nbb = i / 800;
    int rem = i - nbb*800;
    int pp  = rem >> 5;        // 0..24
    int c8  = rem & 31;        // channel octet
    const float* src = xg + ((size_t)(b0+nbb)*256 + c8*8)*25 + pp;
    v8s pk;
    #pragma unroll
    for (int k=0;k<8;++k) pk[k] = (short)f2bf(src[k*25]);
    *(v8s*)(smem + nbb*YSB + pp*CPB + c8*16) = pk;
  }
  __syncthreads();

  if (tid < NB){
    float s=0.f;
    #pragma unroll
    for (int pp=0;pp<25;++pp) s += MS[tid*32+pp];
    INVD[tid] = __builtin_amdgcn_rcpf(fmaxf(s, 1e-8f));
  }

  // ---------------- conv1 (1x1): 16 K-steps of 32x32x16, ring-2 ------------
  v16f acc1_0, acc1_1;
  #pragma unroll
  for (int j=0;j<16;++j){ acc1_0[j]=0.f; acc1_1[j]=0.f; }
  #pragma unroll
  for (int s0=0; s0<2; ++s0){
    B1[s0][0] = *(const v8s*)(b1base[0] + s0*32);
    B1[s0][1] = *(const v8s*)(b1base[1] + s0*32);
  }
  #pragma unroll
  for (int s=0; s<16; ++s){
    __builtin_amdgcn_s_setprio(1);
    acc1_0 = __builtin_amdgcn_mfma_f32_32x32x16_bf16(A1[s&1], B1[s&1][0], acc1_0, 0,0,0);
    acc1_1 = __builtin_amdgcn_mfma_f32_32x32x16_bf16(A1[s&1], B1[s&1][1], acc1_1, 0,0,0);
    __builtin_amdgcn_s_setprio(0);
    if (s+2 < 16){
      A1[s&1] = *(const v8s*)(w1a + (s+2)*8192);
      B1[s&1][0] = *(const v8s*)(b1base[0] + (s+2)*32);
      B1[s&1][1] = *(const v8s*)(b1base[1] + (s+2)*32);
    }
  }

  // conv2 A prologue (global) can start now
  v8s A2[2], B2[2][2];
  A2[0] = *(const v8s*)(w2a);
  A2[1] = *(const v8s*)(w2a + 8192);

  // ---------------- GN1 (wave's 32 ch = one group) + GELU -> rows 0..24 ----
  {
    float s0a=0.f,q0a=0.f,s1a=0.f,q1a=0.f;
    #pragma unroll
    for (int j=0;j<16;++j){
      float v0 = acc1_0[j], v1 = acc1_1[j];
      s0a+=v0; q0a+=v0*v0; s1a+=v1; q1a+=v1*v1;
    }
    #pragma unroll
    for (int off=1; off<64; off<<=1){
      s0a += __shfl_xor(s0a, off, 64); q0a += __shfl_xor(q0a, off, 64);
      s1a += __shfl_xor(s1a, off, 64); q1a += __shfl_xor(q1a, off, 64);
    }
    __syncthreads();   // all conv1 LDS reads complete before in-place overwrite

    float mu0 = s0a*(1.f/800.f), mu1 = s1a*(1.f/800.f);
    float rstd0 = rsqrtf(q0a*(1.f/800.f) - mu0*mu0 + 1e-5f);
    float rstd1 = rsqrtf(q1a*(1.f/800.f) - mu1*mu1 + 1e-5f);
    if (pv){
      #pragma unroll
      for (int nt=0; nt<2; ++nt){
        float mu = nt ? mu1 : mu0, rstd = nt ? rstd1 : rstd0;
        char* dst = smem + nt*YSB + p*CPB + wid*64 + half*8;
        #pragma unroll
        for (int q=0;q<4;++q){
          v4s pk;
          #pragma unroll
          for (int i2=0;i2<4;++i2){
            int ch = wid*32 + q*8 + half*4 + i2;
            float v = nt ? acc1_1[4*q+i2] : acc1_0[4*q+i2];
            float f = (v-mu)*rstd*GB[ch]+GB[256+ch];
            pk[i2] = (short)f2bf(gelu_f(f));
          }
          *(v4s*)(dst + q*16) = pk;
        }
      }
    }
  }
  __syncthreads();   // y1n complete (row 25 still zero)

  // ---------------- conv2: 144 K-steps (9 taps x 16) of 32x32x16, ring-2 ---
  v16f acc2_0, acc2_1;
  #pragma unroll
  for (int j=0;j<16;++j){ acc2_0[j]=0.f; acc2_1[j]=0.f; }

  // B prologue AFTER the barrier (race fix)
  #pragma unroll
  for (int s0=0; s0<2; ++s0){
    B2[s0][0] = *(const v8s*)(smem + roA[0] + s0*32);
    B2[s0][1] = *(const v8s*)(smem + YSB + roA[0] + s0*32);
  }
  #pragma unroll
  for (int s=0; s<144; ++s){
    __builtin_amdgcn_s_setprio(1);
    acc2_0 = __builtin_amdgcn_mfma_f32_32x32x16_bf16(A2[s&1], B2[s&1][0], acc2_0, 0,0,0);
    acc2_1 = __builtin_amdgcn_mfma_f32_32x32x16_bf16(A2[s&1], B2[s&1][1], acc2_1, 0,0,0);
    __builtin_amdgcn_s_setprio(0);
    if (s+2 < 144){
      int s2 = s+2;
      A2[s&1] = *(const v8s*)(w2a + s2*8192);
      int ro = roA[s2>>4];            // compile-time index under full unroll
      int co = (s2&15)*32;
      B2[s&1][0] = *(const v8s*)(smem + ro + co);
      B2[s&1][1] = *(const v8s*)(smem + YSB + ro + co);
    }
  }

  // ---------------- GN2 + GELU + residual -> OUTF (bf16) -------------------
  {
    float s0a=0.f,q0a=0.f,s1a=0.f,q1a=0.f;
    #pragma unroll
    for (int j=0;j<16;++j){
      float v0=acc2_0[j], v1=acc2_1[j];
      s0a+=v0; q0a+=v0*v0; s1a+=v1; q1a+=v1*v1;
    }
    #pragma unroll
    for (int off=1; off<64; off<<=1){
      s0a += __shfl_xor(s0a, off, 64); q0a += __shfl_xor(q0a, off, 64);
      s1a += __shfl_xor(s1a, off, 64); q1a += __shfl_xor(q1a, off, 64);
    }
    __syncthreads();   // conv2 LDS reads done; Y region becomes OUTF

    float mu0 = s0a*(1.f/800.f), mu1 = s1a*(1.f/800.f);
    float rstd0 = rsqrtf(q0a*(1.f/800.f) - mu0*mu0 + 1e-5f);
    float rstd1 = rsqrtf(q1a*(1.f/800.f) - mu1*mu1 + 1e-5f);
    if (pv){
      const float* xr0 = xg + ((size_t)(b0+0)*256 + wid*32)*25 + p;
      const float* xr1 = xg + ((size_t)(b0+1)*256 + wid*32)*25 + p;
      #pragma unroll 4
      for (int j=0;j<16;++j){
        int crow = (j&3) + 8*(j>>2) + 4*half;
        int ch   = wid*32 + crow;
        float f0 = (acc2_0[j]-mu0)*rstd0*GB[512+ch]+GB[768+ch];
        f0 = gelu_f(f0) + xr0[crow*25];
        OUTFu[ch*25 + p] = f2bf(f0);
        float f1 = (acc2_1[j]-mu1)*rstd1*GB[512+ch]+GB[768+ch];
        f1 = gelu_f(f1) + xr1[crow*25];
        OUTFu[6400 + ch*25 + p] = f2bf(f1);
      }
    }
  }
  __syncthreads();

  // ---------------- masked pooling via OUTF re-read ------------------------
  {
    int nbb = tid >> 8, ch = tid & 255;
    const unsigned short* of = OUTFu + nbb*6400 + ch*25;
    const float* ms = MS + nbb*32;
    float dot = 0.f;
    #pragma unroll
    for (int pp=0; pp<25; ++pp) dot = fmaf(bf2f(of[pp]), ms[pp], dot);
    POOL[nbb*256 + ch] = dot;
  }
  __syncthreads();

  // ---------------- SE FC1: 4-way split dot + shuffle combine --------------
  {
    int nbb  = tid >> 8;          // 0..1
    int hid  = (tid >> 2) & 63;
    int part = tid & 3;
    const float* pl = POOL + nbb*256 + part*64;
    const float* wp = fc1t + part*64*64 + hid;
    float dot = 0.f;
    #pragma unroll 8
    for (int c=0;c<64;++c) dot += wp[c*64]*pl[c];
    dot += __shfl_xor(dot, 1, 64);
    dot += __shfl_xor(dot, 2, 64);
    if (part == 0)
      HS[nbb*64+hid] = gelu_f(fmaf(INVD[nbb], dot, fc1b[hid]));
  }
  __syncthreads();
  // ---------------- SE FC2 -> sigmoid gate (LDS + global) ------------------
  {
    int ch = tid & 255, nbb = tid >> 8;
    const float* hp = HS + nbb*64;
    float dot = 0.f;
    #pragma unroll 8
    for (int k=0;k<64;++k) dot += fc2t[k*256+ch]*hp[k];
    dot += fc2b[ch];
    float gv = __builtin_amdgcn_rcpf(1.0f + __builtin_amdgcn_exp2f(-dot*1.4426950408889634f));
    GT[nbb*256+ch] = gv;
    gateg[(size_t)(b0+nbb)*256+ch] = gv;
  }
  __syncthreads();

  // ---------------- final coalesced store: out = OUTF * gate * mask --------
  for (int i = tid; i < NB*800; i += NTHREADS){
    int nbb = (i >= 800);
    int r   = i - nbb*800;
    int e0  = r*8;
    v8s pk = *(const v8s*)(OUTFu + nbb*6400 + e0);
    float o[8];
    #pragma unroll
    for (int k=0;k<8;++k){
      int e = e0+k;
      int ch = e/25;
      int pp = e - ch*25;
      o[k] = bf2f((unsigned short)pk[k]) * GT[nbb*256+ch] * MS[nbb*32+pp];
    }
    float* dst = outg + (size_t)(b0+nbb)*6400 + e0;
    v4f a, b;
    a[0]=o[0]; a[1]=o[1]; a[2]=o[2]; a[3]=o[3];
    b[0]=o[4]; b[1]=o[5]; b[2]=o[6]; b[3]=o[7];
    *(v4f*)(dst)   = a;
    *(v4f*)(dst+4) = b;
  }
}

extern "C" void kernel_launch(void* const* d_in, const int* in_sizes, int n_in,
                              void* d_out, int out_size, void* d_ws, size_t ws_size,
                              hipStream_t stream)
{
  const float* xg   = (const float*)d_in[0];
  const float* pm   = (const float*)d_in[1];
  const float* W1   = (const float*)d_in[2];
  const float* g1   = (const float*)d_in[3];
  const float* b1   = (const float*)d_in[4];
  const float* W2   = (const float*)d_in[5];
  const float* g2   = (const float*)d_in[6];
  const float* b2   = (const float*)d_in[7];
  const float* fc1w = (const float*)d_in[8];
  const float* fc1b = (const float*)d_in[9];
  const float* fc2w = (const float*)d_in[10];
  const float* fc2b = (const float*)d_in[11];

  float* outg  = (float*)d_out;
  float* gateg = outg + (size_t)8192*256*25;

  unsigned short* w1p = (unsigned short*)d_ws;        // 16*256*16 bf16
  unsigned short* w2p = w1p + 16*256*16;              // 144*256*16 bf16
  float* fc1t = (float*)(w2p + 144*256*16);           // 256*64 f32 (transposed)
  float* fc2t = fc1t + 256*64;                        // 64*256 f32 (transposed)

  prep_kernel<<<dim3(512), dim3(256), 0, stream>>>(W1, W2, fc1w, fc2w, w1p, w2p, fc1t, fc2t);

  hipFuncSetAttribute(reinterpret_cast<const void*>(lrb_main),
                      hipFuncAttributeMaxDynamicSharedMemorySize, (int)SMEM_BYTES);
  lrb_main<<<dim3(4096), dim3(NTHREADS), SMEM_BYTES, stream>>>(
      xg, pm, g1, b1, g2, b2, w1p, w2p, fc1t, fc1b, fc2t, fc2b, outg, gateg);
}